// Round 3
// baseline (267.796 us; speedup 1.0000x reference)
//
#include <hip/hip_runtime.h>

// Multi-threshold LIF accumulation.
// x: [T=4, B, N, C] fp32; thresholds: [4] fp32; out: [T, B, N, C] fp32.
// Each thread owns 8 consecutive channel elements (two 16B vectors) of one
// timestep-slab position, loads all T=4 timestep values, runs the
// 4-threshold x 4-timestep LIF recurrence entirely in registers, writes
// outputs. Pure streaming kernel: 154 MB read + 154 MB write, zero reuse
// -> nontemporal loads/stores (nt cache bit) to skip cache allocation.

static constexpr int TT = 4;  // timesteps
static constexpr int JJ = 4;  // threshold blocks
static constexpr int EPT = 8; // elements per thread (two 16B vectors)

typedef float f32x4 __attribute__((ext_vector_type(4)));  // true clang vector:
// accepted by __builtin_nontemporal_load/store (HIP float4 struct is not)

__global__ __launch_bounds__(256) void lif_multithresh_kernel(
    const f32x4* __restrict__ x,
    const float* __restrict__ th,
    f32x4* __restrict__ out,
    int n4)  // f32x4s per timestep slab
{
    const int i0 = (blockIdx.x * blockDim.x + threadIdx.x) * 2;  // first vec idx
    if (i0 >= n4) return;
    const int i1 = i0 + 1;  // n4 is even (S % 8 == 0)

    // Load all timesteps for this position (32B per lane per timestep).
    float xv[TT][EPT];
#pragma unroll
    for (int t = 0; t < TT; ++t) {
        const f32x4 a = __builtin_nontemporal_load(&x[(size_t)t * (size_t)n4 + (size_t)i0]);
        const f32x4 b = __builtin_nontemporal_load(&x[(size_t)t * (size_t)n4 + (size_t)i1]);
        xv[t][0] = a.x; xv[t][1] = a.y; xv[t][2] = a.z; xv[t][3] = a.w;
        xv[t][4] = b.x; xv[t][5] = b.y; xv[t][6] = b.z; xv[t][7] = b.w;
    }

    float thr[JJ];
#pragma unroll
    for (int j = 0; j < JJ; ++j) thr[j] = th[j];

    float acc[TT][EPT];
#pragma unroll
    for (int t = 0; t < TT; ++t)
#pragma unroll
        for (int c = 0; c < EPT; ++c) acc[t][c] = 0.0f;

    // LIF: v = v + (x - v)/tau (tau = 2, exact * 0.5), spike = (v >= th),
    // hard reset v = 0 on spike. Op order matches the reference exactly,
    // so spike decisions are bit-identical.
#pragma unroll
    for (int j = 0; j < JJ; ++j) {
        const float tj = thr[j];
#pragma unroll
        for (int c = 0; c < EPT; ++c) {
            float v = 0.0f;
#pragma unroll
            for (int t = 0; t < TT; ++t) {
                v = v + (xv[t][c] - v) * 0.5f;
                const bool s = (v >= tj);
                acc[t][c] += s ? 1.0f : 0.0f;
                v = s ? 0.0f : v;
            }
        }
    }

#pragma unroll
    for (int t = 0; t < TT; ++t) {
        f32x4 oa, ob;
        oa.x = acc[t][0]; oa.y = acc[t][1]; oa.z = acc[t][2]; oa.w = acc[t][3];
        ob.x = acc[t][4]; ob.y = acc[t][5]; ob.z = acc[t][6]; ob.w = acc[t][7];
        __builtin_nontemporal_store(oa, &out[(size_t)t * (size_t)n4 + (size_t)i0]);
        __builtin_nontemporal_store(ob, &out[(size_t)t * (size_t)n4 + (size_t)i1]);
    }
}

extern "C" void kernel_launch(void* const* d_in, const int* in_sizes, int n_in,
                              void* d_out, int out_size, void* d_ws, size_t ws_size,
                              hipStream_t stream) {
    const float* x  = (const float*)d_in[0];
    const float* th = (const float*)d_in[1];
    float* out = (float*)d_out;

    const int total = in_sizes[0];       // T*B*N*C
    const int S = total / TT;            // B*N*C per timestep
    const int n4 = S / 4;                // f32x4s per timestep (S % 4 == 0)

    const int block = 256;
    const int threads_needed = (n4 + 1) / 2;  // 2 vectors per thread
    const int grid = (threads_needed + block - 1) / block;
    lif_multithresh_kernel<<<grid, block, 0, stream>>>(
        (const f32x4*)x, th, (f32x4*)out, n4);
}